// Round 8
// baseline (167.114 us; speedup 1.0000x reference)
//
#include <hip/hip_runtime.h>
#include <math.h>

// SparseMOELayer: N=65536 tokens, D=128, E=16 experts, top-3 routing.
// Outputs concat: logits[N*D] | importance_loss[1] | comb[N*E]
//
// R8: PHASE SPLIT. R7 falsified occupancy (39% occ, dur worse); R5 falsified
// LDS; pipes all <40% at any occupancy => the wall is the serial phase
// convoy inside one kernel. Split:
//   k_gate: G1-G5 (fp64 gate, top-3, comb -> out, importance). No MFMA,
//           low VGPR, LDS 61K, VALU-bound.
//   k_exp : R6's X-phases verbatim (bf16 x staging, comb read back from
//           out, be, register-resident MFMA expert loop, yacc store).
//           B-prefetch issued at kernel entry.
// comb handoff via the required `out` write (fp32 roundtrip = identical
// values; comb region is only 4B-aligned (+1 float) -> scalar reads).
// All arithmetic byte-identical to R6 -> bit-identical outputs.
// NOT changed: k_prep, k_loss, launch_bounds lessons (R1/R3).
#define NTOK 65536
#define DD   128
#define NE   16
#define NK   3
#define TPB  64                    // tokens per block
#define NBLK (NTOK / TPB)          // 1024

#define OUT_LOSS ((size_t)NTOK * DD)
#define OUT_COMB ((size_t)NTOK * DD + 1)

typedef __bf16 bf16x8 __attribute__((ext_vector_type(8)));
typedef __bf16 bf16x4 __attribute__((ext_vector_type(4)));
typedef float  f32x4  __attribute__((ext_vector_type(4)));

__device__ __forceinline__ double softplus_d(double z) {
    return fmax(z, 0.0) + log1p(exp(-fabs(z)));
}

// ---------------------------------------------------------------------------
// K0: pack We[e][d][f] fp32 -> WeTp bf16, FRAGMENT-MAJOR:
//   WeTp[e][nt][s][lane][j]  (flat: e*16384 + (nt*4+s)*512 + lane*8 + j)
//   holds We[d = s*32 + (lane>>4)*8 + j][f = nt*16 + (lane&15)].
// Consumer reads one bf16x8/lane at consecutive 16B -> each B-frag load is
// ONE coalesced 1KB transaction.
// 64 blocks: (expert e = blk>>2, k-step s = blk&3). Block 0 zeroes imp_g.
// ---------------------------------------------------------------------------
__global__ __launch_bounds__(256) void k_prep(
    const float* __restrict__ We, __bf16* __restrict__ WeTp,
    float* __restrict__ imp_g)
{
    __shared__ __bf16 S[32][DD + 8];
    const int tid = threadIdx.x;
    const int e  = blockIdx.x >> 2;
    const int qd = blockIdx.x & 3;             // == k-step s
    if (blockIdx.x == 0 && tid < NE) imp_g[tid] = 0.f;
    const size_t base = (size_t)e * DD * DD + (size_t)qd * 32 * DD;
    for (int i = tid; i < 32 * DD; i += 256) { // coalesced read, d-quarter
        int dd = i >> 7, f = i & 127;
        S[dd][f] = (__bf16)We[base + i];
    }
    __syncthreads();
    #pragma unroll
    for (int it = 0; it < 2; it++) {
        int lin  = it * 256 + tid;             // 0..511 vectors
        int nt   = lin >> 6;
        int lane = lin & 63;
        int quad = lane >> 4, l15 = lane & 15;
        int f = nt * 16 + l15;
        bf16x8 vv;
        #pragma unroll
        for (int j = 0; j < 8; j++) vv[j] = S[quad * 8 + j][f];
        *(bf16x8*)(WeTp + (size_t)e * 16384 +
                   ((size_t)(nt * 4 + qd) * 64 + lane) * 8) = vv;   // coalesced
    }
}

// ---------------------------------------------------------------------------
// K1a: GATE kernel. 64 tokens/block, 256 threads. Pure VALU/mem.
// Stage x fp32 + gate weights -> fp64 dots (q-outer, W-hoisted; R6 chain
// order -> bit-identical gate) -> top-3 -> comb scalar write to out ->
// importance atomics. LDS ~61K; no MFMA, low VGPR -> VALU-bound.
// ---------------------------------------------------------------------------
__global__ __launch_bounds__(256) void k_gate(
    const float* __restrict__ x, const float* __restrict__ noise,
    const float* __restrict__ Wg, const float* __restrict__ bg,
    const float* __restrict__ Wn, const float* __restrict__ bn,
    float* __restrict__ out, float* __restrict__ imp_g)
{
    __shared__ float xs[TPB][DD + 4];                                  // 33.8K
    __shared__ struct { float WgT[NE][DD + 4]; float WnT[NE][DD + 4]; } w; // 16.9K
    __shared__ double ga[TPB][NE + 1];                                 // 8.7K
    __shared__ float tkw[TPB][NK];
    __shared__ int   tke[TPB][NK];
    __shared__ float impS[NE];

    const int tid = threadIdx.x;
    const int n0  = blockIdx.x * TPB;
    const int e16 = tid & 15;              // expert id
    const int tl  = tid >> 4;              // token lane 0..15

    // ---- G1: stage x fp32 + gate weights; zero impS ----
    if (tid < NE) impS[tid] = 0.0f;
    for (int i = tid; i < DD * NE; i += 256) {
        int d = i >> 4, ee = i & 15;
        w.WgT[ee][d] = Wg[i];
        w.WnT[ee][d] = Wn[i];
    }
    for (int idx = tid; idx < TPB * DD / 4; idx += 256) {   // coalesced float4
        int t = idx >> 5, q = idx & 31;
        *(f32x4*)&xs[t][q * 4] =
            *(const f32x4*)(x + (size_t)(n0 + t) * DD + q * 4);
    }
    __syncthreads();

    // ---- G2+G3: fp64 dots, q-outer, fed from LDS (R6 verbatim) ----
    {
        const f32x4* wgp = (const f32x4*)&w.WgT[e16][0];
        const f32x4* wnp = (const f32x4*)&w.WnT[e16][0];

        double Ga[4][4], Ha[4][4];
        #pragma unroll
        for (int g = 0; g < 4; g++)
            #pragma unroll
            for (int j = 0; j < 4; j++) { Ga[g][j] = 0.0; Ha[g][j] = 0.0; }

        #pragma unroll 2
        for (int q = 0; q < DD / 4; q++) {
            f32x4 wg = wgp[q], wn = wnp[q];
            double wg0 = (double)wg[0], wg1 = (double)wg[1];
            double wg2 = (double)wg[2], wg3 = (double)wg[3];
            double wn0 = (double)wn[0], wn1 = (double)wn[1];
            double wn2 = (double)wn[2], wn3 = (double)wn[3];
            f32x4 xv[4];
            #pragma unroll
            for (int g = 0; g < 4; g++)
                xv[g] = *(const f32x4*)&xs[g * 16 + tl][q * 4];
            #pragma unroll
            for (int g = 0; g < 4; g++) {
                double x0 = (double)xv[g][0], x1 = (double)xv[g][1];
                double x2 = (double)xv[g][2], x3 = (double)xv[g][3];
                Ga[g][0] += x0 * wg0; Ga[g][1] += x1 * wg1;
                Ga[g][2] += x2 * wg2; Ga[g][3] += x3 * wg3;
                Ha[g][0] += x0 * wn0; Ha[g][1] += x1 * wn1;
                Ha[g][2] += x2 * wn2; Ha[g][3] += x3 * wn3;
            }
        }

        const double bge = (double)bg[e16], bne = (double)bn[e16];
        #pragma unroll
        for (int g = 0; g < 4; g++) {
            int t = g * 16 + tl;
            double gsum = (Ga[g][0] + Ga[g][1]) + (Ga[g][2] + Ga[g][3]);
            double hsum = (Ha[g][0] + Ha[g][1]) + (Ha[g][2] + Ha[g][3]);
            double nz = (double)noise[(size_t)(n0 + t) * NE + e16];
            ga[t][e16] = gsum + bge + nz * softplus_d(hsum + bne);
        }
    }
    __syncthreads();

    // ---- G4: top-3 + softmax (64 threads; proven code) ----
    if (tid < TPB) {
        int t = tid;
        double vk[NK]; int ix[NK];
        unsigned taken = 0;
        for (int k = 0; k < NK; k++) {
            double best = -INFINITY; int bi = 0;
            for (int j = 0; j < NE; j++) {
                if (!((taken >> j) & 1u)) {
                    double gv = ga[t][j];
                    if (gv > best) { best = gv; bi = j; }  // strict >: low idx tie
                }
            }
            taken |= 1u << bi;
            vk[k] = best; ix[k] = bi;
        }
        double e1 = exp(vk[1] - vk[0]);
        double e2 = exp(vk[2] - vk[0]);
        double inv = 1.0 / (1.0 + e1 + e2);
        tke[t][0] = ix[0]; tke[t][1] = ix[1]; tke[t][2] = ix[2];
        tkw[t][0] = (float)inv;
        tkw[t][1] = (float)(e1 * inv);
        tkw[t][2] = (float)(e2 * inv);
    }
    __syncthreads();

    // ---- G5: comb -> out (scalar, coalesced by e16), impS -> imp_g ----
    for (int g = 0; g < 4; g++) {
        int t = g * 16 + tl;
        float c = 0.f;
        if (tke[t][0] == e16) c = tkw[t][0];
        if (tke[t][1] == e16) c = tkw[t][1];
        if (tke[t][2] == e16) c = tkw[t][2];
        out[OUT_COMB + (size_t)(n0 + t) * NE + e16] = c;
        if (c != 0.f) atomicAdd(&impS[e16], c);
    }
    __syncthreads();
    if (tid < NE) atomicAdd(&imp_g[tid], impS[tid]);
}

// ---------------------------------------------------------------------------
// K1b: EXPERT kernel. 64 tokens/block, 4 waves; wave -> cols wid*32..+31.
// Entry: prefetch expert-0 B frags (L2 latency under staging). Stage x as
// bf16 (R5-proven float4->bf16x4), comb read back from out (scalar; region
// is 4B-aligned), be. Then R6's X2/X3/X4 verbatim: register-resident Af,
// dbuf coalesced B, fmaf combine, bias epilogue, yacc coalesced store.
// LDS ~46.4K: union u {xsb 17.4K | yacc 33.8K}, v {beS 8K + combT 8.4K}.
// MFMA 16x16x32 layouts (m89-verified):
//   A: lane l holds A[m=l&15][k=(l>>4)*8+j]; D: col=l&15, row=(l>>4)*4+reg
// ---------------------------------------------------------------------------
__global__ __launch_bounds__(256, 2) void k_exp(
    const float* __restrict__ x, const __bf16* __restrict__ WeTp,
    const float* __restrict__ be, float* __restrict__ out)
{
    __shared__ union {
        __bf16 xsb[TPB][DD + 8];                                       // 17.4K
        float  yacc[TPB][DD + 4];                                      // 33.8K
    } u;
    __shared__ struct { float beS[NE][DD]; float combT[NE][TPB + 4]; } p;
    const int tid  = threadIdx.x;
    const int n0   = blockIdx.x * TPB;
    const int lane = tid & 63;
    const int wid  = tid >> 6;             // wave -> cols wid*32..+31
    const int l15  = lane & 15;
    const int quad = lane >> 4;

    // ---- prefetch expert-0 B fragments (hide L2 latency under staging) ----
    bf16x8 Bf[2][2][4];
    {
        const __bf16* b = WeTp + (size_t)lane * 8;
        #pragma unroll
        for (int t2 = 0; t2 < 2; t2++)
            #pragma unroll
            for (int s = 0; s < 4; s++)
                Bf[0][t2][s] = *(const bf16x8*)(b + ((wid * 2 + t2) * 4 + s) * 512);
    }

    // ---- X1: stage xsb bf16 (vec), combT (scalar transpose), beS ----
    for (int idx = tid; idx < TPB * DD / 4; idx += 256) {
        int t = idx >> 5, q = idx & 31;
        float4 xv = *(const float4*)(x + (size_t)(n0 + t) * DD + q * 4);
        bf16x4 bv = { (__bf16)xv.x, (__bf16)xv.y, (__bf16)xv.z, (__bf16)xv.w };
        *(bf16x4*)&u.xsb[t][q * 4] = bv;
    }
    {
        const float* combSrc = out + OUT_COMB + (size_t)n0 * NE;
        for (int idx = tid; idx < TPB * NE; idx += 256) {
            int t = idx >> 4, e = idx & 15;
            p.combT[e][t] = combSrc[idx];          // coalesced read, LDS scatter
        }
    }
    for (int idx = tid; idx < NE * DD; idx += 256)
        p.beS[idx >> 7][idx & 127] = be[idx];
    __syncthreads();

    // ---- X2: hoist A fragments (read LDS once) ----
    bf16x8 Af[4][4];
    #pragma unroll
    for (int a = 0; a < 4; a++)
        #pragma unroll
        for (int s = 0; s < 4; s++)
            Af[a][s] = *(const bf16x8*)&u.xsb[a * 16 + l15][32 * s + quad * 8];
    __syncthreads();   // xsb dead -> u.yacc reusable

    // ---- X3: expert loop, register-resident, dbuf coalesced B ----
    f32x4 logits[4][2];
    #pragma unroll
    for (int a = 0; a < 4; a++) {
        logits[a][0] = (f32x4){0.f, 0.f, 0.f, 0.f};
        logits[a][1] = (f32x4){0.f, 0.f, 0.f, 0.f};
    }

    #pragma unroll 2
    for (int e = 0; e < NE; e++) {
        const int cur = e & 1;
        if (e + 1 < NE) {
            const __bf16* b = WeTp + (size_t)(e + 1) * 16384 + (size_t)lane * 8;
            #pragma unroll
            for (int t2 = 0; t2 < 2; t2++)
                #pragma unroll
                for (int s = 0; s < 4; s++)
                    Bf[cur ^ 1][t2][s] =
                        *(const bf16x8*)(b + ((wid * 2 + t2) * 4 + s) * 512);
        }

        f32x4 acc[4][2];
        #pragma unroll
        for (int a = 0; a < 4; a++) {
            acc[a][0] = (f32x4){0.f, 0.f, 0.f, 0.f};
            acc[a][1] = (f32x4){0.f, 0.f, 0.f, 0.f};
        }
        #pragma unroll
        for (int s = 0; s < 4; s++)        // s-outer: 8 indep chains
            #pragma unroll
            for (int a = 0; a < 4; a++) {
                acc[a][0] = __builtin_amdgcn_mfma_f32_16x16x32_bf16(
                    Af[a][s], Bf[cur][0][s], acc[a][0], 0, 0, 0);
                acc[a][1] = __builtin_amdgcn_mfma_f32_16x16x32_bf16(
                    Af[a][s], Bf[cur][1][s], acc[a][1], 0, 0, 0);
            }
        #pragma unroll
        for (int a = 0; a < 4; a++) {
            f32x4 cv = *(const f32x4*)&p.combT[e][a * 16 + quad * 4];
            #pragma unroll
            for (int r = 0; r < 4; r++) {
                logits[a][0][r] = fmaf(cv[r], acc[a][0][r], logits[a][0][r]);
                logits[a][1][r] = fmaf(cv[r], acc[a][1][r], logits[a][1][r]);
            }
        }
    }

    // ---- X4: bias epilogue + single-phase yacc coalesced store ----
    const int nA = wid * 32, nB = nA + 16;
    #pragma unroll 4
    for (int e = 0; e < NE; e++) {
        float bA = p.beS[e][nA + l15];
        float bB = p.beS[e][nB + l15];
        #pragma unroll
        for (int a = 0; a < 4; a++) {
            f32x4 cv = *(const f32x4*)&p.combT[e][a * 16 + quad * 4];
            #pragma unroll
            for (int r = 0; r < 4; r++) {
                logits[a][0][r] = fmaf(cv[r], bA, logits[a][0][r]);
                logits[a][1][r] = fmaf(cv[r], bB, logits[a][1][r]);
            }
        }
    }
    #pragma unroll
    for (int a = 0; a < 4; a++) {
        #pragma unroll
        for (int r = 0; r < 4; r++) {
            int row = a * 16 + quad * 4 + r;
            u.yacc[row][nA + l15] = logits[a][0][r];
            u.yacc[row][nB + l15] = logits[a][1][r];
        }
    }
    __syncthreads();
    float4* op4 = (float4*)(out + (size_t)n0 * DD);
    for (int idx = tid; idx < TPB * DD / 4; idx += 256) {
        int t = idx >> 5, q = idx & 31;
        op4[idx] = *(const float4*)&u.yacc[t][q * 4];
    }
}

// ---------------------------------------------------------------------------
// K2: loss from 16 globally-accumulated importances (atomic sums from k_gate).
// ---------------------------------------------------------------------------
__global__ __launch_bounds__(64) void k_loss(
    const float* __restrict__ imp_g, float* __restrict__ out)
{
    if (threadIdx.x == 0) {
        double mean = 0.0;
        for (int i = 0; i < NE; i++) mean += (double)imp_g[i];
        mean /= NE;
        double var = 0.0;
        for (int i = 0; i < NE; i++) {
            double d = (double)imp_g[i] - mean; var += d * d;
        }
        var /= (NE - 1);                    // ddof=1
        out[OUT_LOSS] = (float)(var / (mean * mean));
    }
}

// ---------------------------------------------------------------------------
extern "C" void kernel_launch(void* const* d_in, const int* in_sizes, int n_in,
                              void* d_out, int out_size, void* d_ws, size_t ws_size,
                              hipStream_t stream)
{
    (void)in_sizes; (void)n_in; (void)out_size; (void)ws_size;
    const float* x     = (const float*)d_in[0];
    const float* noise = (const float*)d_in[1];
    const float* Wg    = (const float*)d_in[2];
    const float* bg    = (const float*)d_in[3];
    const float* Wn    = (const float*)d_in[4];
    const float* bn    = (const float*)d_in[5];
    const float* We    = (const float*)d_in[6];
    const float* be    = (const float*)d_in[7];
    float* out = (float*)d_out;

    char*   ws    = (char*)d_ws;
    float*  imp_g = (float*)ws;                  // 64 B (16 floats)
    __bf16* WeTp  = (__bf16*)(ws + 1024);        // 512 KB, 16B-aligned

    hipLaunchKernelGGL(k_prep, dim3(64), dim3(256), 0, stream,
                       We, WeTp, imp_g);
    hipLaunchKernelGGL(k_gate, dim3(NBLK), dim3(256), 0, stream,
                       x, noise, Wg, bg, Wn, bn, out, imp_g);
    hipLaunchKernelGGL(k_exp, dim3(NBLK), dim3(256), 0, stream,
                       x, WeTp, be, out);
    hipLaunchKernelGGL(k_loss, dim3(1), dim3(64), 0, stream, imp_g, out);
}